// Round 10
// baseline (306.013 us; speedup 1.0000x reference)
//
#include <hip/hip_runtime.h>
#include <cstdint>

#define NN 50000
#define NE 600000

typedef unsigned short ushort_t;
typedef __bf16 bf16_t;
typedef __attribute__((ext_vector_type(8))) bf16_t bf16x8;
typedef __attribute__((ext_vector_type(8))) ushort_t ushort8;
typedef __attribute__((ext_vector_type(4))) float f32x4;

// ---- ws layout (float offsets), extent 19,341,472 fl = 77.37 MB ----
// WT   : [128 cols][640 k] bf16     @ 0           (81,920 ushorts = 40,960 fl)
// XG   : [3125 tiles][80 g][16 rows][8] bf16 @ 40,960   (32M ushorts = 16M fl)
//        g 0..15 = X k-cols 0..127; g 16..79 = G (4 bases x 128), kk = g*8
// Xbf  : [NN][128] bf16 (node-major, gather source) @ 16,040,960  (3.2M fl)
// cnt  : [NN] i32                   @ 19,240,960
// curs : [NN] i32                   @ 19,290,960
// bsum/bscan : 128+128 i32          @ 19,340,960 / 19,341,088
// colsum/colsq : 128+128 f32        @ 19,341,216 / 19,341,344
#define WT_OFF   0ul
#define XG_OFF   40960ul
#define XBF_OFF  16040960ul
#define CNT_OFF  19240960ul
#define CUR_OFF  19290960ul
#define BSUM_OFF 19340960ul
#define BSCN_OFF 19341088ul
#define CS_OFF   19341216ul
#define CSQ_OFF  19341344ul
// d_out transient: epack [NE] u32 @ 0 (scatter -> gather; dead before k_gemm_f)

__device__ __forceinline__ float2 bf2_to_f2(uint32_t u) {
    float2 r;
    r.x = __uint_as_float(u << 16);
    r.y = __uint_as_float(u & 0xffff0000u);
    return r;
}

__device__ __forceinline__ ushort_t f2bf(float f) {
    uint32_t u = __float_as_uint(f);
    u = (u + 0x7fffu + ((u >> 16) & 1u)) >> 16;   // RNE
    return (ushort_t)u;
}

__device__ __forceinline__ uint32_t f2bf2(float x, float y) {
    return (uint32_t)f2bf(x) | ((uint32_t)f2bf(y) << 16);
}

__device__ __forceinline__ void async_copy16(const void* g, void* l) {
    __builtin_amdgcn_global_load_lds(
        (const __attribute__((address_space(1))) void*)g,
        (__attribute__((address_space(3))) void*)l, 16, 0, 0);
}

// ---------------------------------------------------------------------------
// K0: WT[n][kk] bf16; kk<128 -> Wl[kk][n]; kk>=128: j=kk-128 (=b*128+i) ->
// bases[b][i][n].  kk-order matches XG fragment order (kk = g*8).
// ---------------------------------------------------------------------------
__global__ __launch_bounds__(256) void k_prep(
    const float* __restrict__ Wl, const float* __restrict__ bases,
    ushort_t* __restrict__ WT)
{
    const int i = blockIdx.x * 256 + threadIdx.x;
    if (i >= 128 * 640) return;
    const int n = i / 640;
    const int kk = i - n * 640;
    float v;
    if (kk < 128) v = Wl[kk * 128 + n];
    else {
        const int j = kk - 128;
        v = bases[(size_t)(j >> 7) * 16384 + (j & 127) * 128 + n];
    }
    WT[i] = f2bf(v);
}

// ---------------------------------------------------------------------------
// K0b: per 16-node tile: write Xbf (node-major) + XG X-part (fragment order)
// via an LDS transpose (pad 136 ushorts/row -> 2-way max on both phases).
// ---------------------------------------------------------------------------
__global__ __launch_bounds__(256) void k_cast(
    const float* __restrict__ X, ushort_t* __restrict__ Xbf,
    ushort_t* __restrict__ XG)
{
    __shared__ ushort_t L[16][136];
    const int tid = threadIdx.x;
    const int tile = blockIdx.x;
    {
        const int row = tid >> 4, gc = tid & 15;
        const int node = tile * 16 + row;           // grid=3125 -> node<NN
        const float4* p = (const float4*)(X + (size_t)node * 128 + gc * 8);
        const float4 a = p[0], b = p[1];
        ushort_t t8[8] = { f2bf(a.x), f2bf(a.y), f2bf(a.z), f2bf(a.w),
                           f2bf(b.x), f2bf(b.y), f2bf(b.z), f2bf(b.w) };
        const uint4 v = *(const uint4*)t8;
        *(uint4*)&L[row][gc * 8] = v;
        *(uint4*)(Xbf + (size_t)node * 128 + gc * 8) = v;   // coalesced
    }
    __syncthreads();
    {
        const int g = tid >> 4, r2 = tid & 15;
        const uint4 u = *(const uint4*)&L[r2][g * 8];
        // lane-linear: g*256B + r2*16B -> contiguous 1KB per wave
        *(uint4*)(XG + (size_t)tile * 10240 + g * 128 + r2 * 8) = u;
    }
}

// ---------------------------------------------------------------------------
// K2: histogram of dst -> cnt
// ---------------------------------------------------------------------------
__global__ __launch_bounds__(256) void k_hist(
    const int* __restrict__ eidx, int* __restrict__ cnt)
{
    const int* __restrict__ dst = eidx + NE;
    for (int e = blockIdx.x * 256 + threadIdx.x; e < NE; e += gridDim.x * 256)
        atomicAdd(cnt + dst[e], 1);
}

// ---------------------------------------------------------------------------
// K3a/b/c: exclusive scan of cnt -> curs
// ---------------------------------------------------------------------------
__global__ __launch_bounds__(256) void k_scan1(
    const int* __restrict__ cnt, int* __restrict__ curs, int* __restrict__ bsum)
{
    __shared__ int sh[256];
    const int tid = threadIdx.x;
    const int i0 = blockIdx.x * 512 + tid * 2;
    const int v0 = (i0 < NN) ? cnt[i0] : 0;
    const int v1 = (i0 + 1 < NN) ? cnt[i0 + 1] : 0;
    int s = v0 + v1;
    sh[tid] = s;
    __syncthreads();
#pragma unroll
    for (int off = 1; off < 256; off <<= 1) {
        int t = (tid >= off) ? sh[tid - off] : 0;
        __syncthreads();
        sh[tid] += t;
        __syncthreads();
    }
    const int excl = sh[tid] - s;
    if (i0 < NN) curs[i0] = excl;
    if (i0 + 1 < NN) curs[i0 + 1] = excl + v0;
    if (tid == 255) bsum[blockIdx.x] = sh[255];
}

__global__ __launch_bounds__(128) void k_scan2(
    const int* __restrict__ bsum, int* __restrict__ bscan, int nblk)
{
    __shared__ int sh[128];
    const int tid = threadIdx.x;
    int v = (tid < nblk) ? bsum[tid] : 0;
    sh[tid] = v;
    __syncthreads();
#pragma unroll
    for (int off = 1; off < 128; off <<= 1) {
        int t = (tid >= off) ? sh[tid - off] : 0;
        __syncthreads();
        sh[tid] += t;
        __syncthreads();
    }
    if (tid < nblk) bscan[tid] = sh[tid] - v;
}

__global__ __launch_bounds__(256) void k_scan3(
    int* __restrict__ curs, const int* __restrict__ bscan)
{
    const int add = bscan[blockIdx.x];
    const int i0 = blockIdx.x * 512 + threadIdx.x * 2;
    if (i0 < NN) curs[i0] += add;
    if (i0 + 1 < NN) curs[i0 + 1] += add;
}

// ---------------------------------------------------------------------------
// K4: scatter edges into CSR slots. epack = src | (type<<16).
// ---------------------------------------------------------------------------
__global__ __launch_bounds__(256) void k_scatter(
    const int* __restrict__ eidx, const int* __restrict__ etype,
    int* __restrict__ curs, uint32_t* __restrict__ epack)
{
    const int* __restrict__ src = eidx;
    const int* __restrict__ dst = eidx + NE;
    for (int e = blockIdx.x * 256 + threadIdx.x; e < NE; e += gridDim.x * 256) {
        const int d = dst[e];
        const int pos = atomicAdd(curs + d, 1);
        epack[pos] = (uint32_t)src[e] | ((uint32_t)etype[e] << 16);
    }
}

// ---------------------------------------------------------------------------
// K5: gather raw X rows (256 B/edge) into XG G-part (fragment order).
// Block owns one 16-node tile (writes stay XCD-local); wave w -> 4 nodes.
// Basis b, cols (2L,2L+1): kk = 128+b*128+2L -> g = 16+b*16+(L>>2),
// in-group dword offset = L&3.
// ---------------------------------------------------------------------------
__device__ __forceinline__ void edge_accum(
    uint32_t ep, const ushort_t* __restrict__ Xbf,
    const float* __restrict__ coeff, int lane,
    float2& m0, float2& m1, float2& m2, float2& m3)
{
    const int s = ep & 0xffff;
    const int t = ep >> 16;
    const float4 cw = *(const float4*)(coeff + t * 4);
    const uint32_t xv = *(const uint32_t*)(Xbf + (size_t)s * 128 + lane * 2);
    const float2 x = bf2_to_f2(xv);
    m0.x += cw.x * x.x; m0.y += cw.x * x.y;
    m1.x += cw.y * x.x; m1.y += cw.y * x.y;
    m2.x += cw.z * x.x; m2.y += cw.z * x.y;
    m3.x += cw.w * x.x; m3.y += cw.w * x.y;
}

__global__ __launch_bounds__(256) void k_gather(
    const ushort_t* __restrict__ Xbf, const uint32_t* __restrict__ epack,
    const int* __restrict__ cnt, const int* __restrict__ curs,
    const float* __restrict__ coeff, ushort_t* __restrict__ XG)
{
    const int lane = threadIdx.x & 63;
    const int w = threadIdx.x >> 6;
    const int tile = blockIdx.x;
    uint32_t* __restrict__ gbase = (uint32_t*)(XG + (size_t)tile * 10240);
    const int wbase = (16 + (lane >> 2)) * 64 + (lane & 3);

    for (int i = 0; i < 4; ++i) {
        const int d = tile * 16 + w * 4 + i;     // grid=3125 -> d<NN
        const int n = cnt[d];
        const int end = curs[d];
        int j = end - n;

        float2 m0 = {0.f, 0.f}, m1 = {0.f, 0.f}, m2 = {0.f, 0.f}, m3 = {0.f, 0.f};
        for (; j + 3 < end; j += 4) {
            const uint32_t e0 = epack[j];
            const uint32_t e1 = epack[j + 1];
            const uint32_t e2 = epack[j + 2];
            const uint32_t e3 = epack[j + 3];
            edge_accum(e0, Xbf, coeff, lane, m0, m1, m2, m3);
            edge_accum(e1, Xbf, coeff, lane, m0, m1, m2, m3);
            edge_accum(e2, Xbf, coeff, lane, m0, m1, m2, m3);
            edge_accum(e3, Xbf, coeff, lane, m0, m1, m2, m3);
        }
        for (; j < end; ++j) edge_accum(epack[j], Xbf, coeff, lane, m0, m1, m2, m3);

        const int word = wbase + (d & 15) * 4;
        gbase[word]        = f2bf2(m0.x, m0.y);   // basis 0
        gbase[word + 1024] = f2bf2(m1.x, m1.y);   // +16 groups
        gbase[word + 2048] = f2bf2(m2.x, m2.y);
        gbase[word + 3072] = f2bf2(m3.x, m3.y);
    }
}

// ---------------------------------------------------------------------------
// K6: FUSED projection. Block = 32 rows (2 tiles) x 128 cols, grid 1563.
// Stage: 40 x 1KB async global_load_lds (contiguous both sides); LDS layout
// == lane order -> ds_read_b128 conflict-free by construction. 4 waves,
// wave = 32 cols; K=640 fully unrolled: 2 B-loads + 2 ds_read + 4 MFMA/chunk.
// Epilogue: degree-norm + column stats.  LDS 40,960 B -> 4 blocks/CU.
// ---------------------------------------------------------------------------
__global__ __launch_bounds__(256) void k_gemm_f(
    const ushort_t* __restrict__ XG, const ushort_t* __restrict__ WT,
    const float* __restrict__ bl, const int* __restrict__ cnt,
    float* __restrict__ out, float* __restrict__ colsum,
    float* __restrict__ colsq)
{
    __shared__ ushort_t As[2][10240];
    const int tid = threadIdx.x;
    const int lane = tid & 63;
    const int w = tid >> 6;
    const int row0 = blockIdx.x * 32;
    const int tile0 = blockIdx.x * 2;

    // async stage: wave w fires 10 x 1KB (tile 3125 OOB reads land in Xbf; rows guarded)
#pragma unroll
    for (int k = 0; k < 10; ++k) {
        const int s = w * 10 + k;
        const int tl = s >= 20 ? 1 : 0;
        const int off = s - tl * 20;
        const ushort_t* src = XG + (size_t)(tile0 + tl) * 10240 + off * 512 + lane * 8;
        async_copy16(src, &As[tl][off * 512]);
    }
    __syncthreads();   // drains vmcnt

    const int m = lane & 15;
    const int quad = lane >> 4;
    const ushort_t* bp0 = WT + (size_t)(w * 32 + m) * 640 + quad * 8;
    const ushort_t* bp1 = bp0 + 16 * 640;

    f32x4 cc[2][2];
#pragma unroll
    for (int rt = 0; rt < 2; ++rt)
#pragma unroll
        for (int ct = 0; ct < 2; ++ct)
#pragma unroll
            for (int i = 0; i < 4; ++i) cc[rt][ct][i] = 0.f;

#pragma unroll
    for (int c = 0; c < 20; ++c) {
        const bf16x8 b0 = __builtin_bit_cast(bf16x8, *(const ushort8*)(bp0 + c * 32));
        const bf16x8 b1 = __builtin_bit_cast(bf16x8, *(const ushort8*)(bp1 + c * 32));
        const int aoff = (c * 4 + quad) * 128 + m * 8;   // == (c*1024B + lane*16B)
        const bf16x8 a0 = __builtin_bit_cast(bf16x8, *(const ushort8*)&As[0][aoff]);
        const bf16x8 a1 = __builtin_bit_cast(bf16x8, *(const ushort8*)&As[1][aoff]);
        cc[0][0] = __builtin_amdgcn_mfma_f32_16x16x32_bf16(a0, b0, cc[0][0], 0, 0, 0);
        cc[0][1] = __builtin_amdgcn_mfma_f32_16x16x32_bf16(a0, b1, cc[0][1], 0, 0, 0);
        cc[1][0] = __builtin_amdgcn_mfma_f32_16x16x32_bf16(a1, b0, cc[1][0], 0, 0, 0);
        cc[1][1] = __builtin_amdgcn_mfma_f32_16x16x32_bf16(a1, b1, cc[1][1], 0, 0, 0);
    }

    // epilogue: degree-norm, store, column stats
    const float blv0 = bl[w * 32 + m];
    const float blv1 = bl[w * 32 + 16 + m];
    float s0 = 0.f, q0 = 0.f, s1 = 0.f, q1 = 0.f;

#pragma unroll
    for (int rt = 0; rt < 2; ++rt) {
        const int rowb = row0 + rt * 16 + quad * 4;
#pragma unroll
        for (int r = 0; r < 4; ++r) {
            const int row = rowb + r;
            if (row < NN) {
                const int dg = cnt[row];
                const float inv = 1.0f / (float)((dg > 0) ? dg : 1);
                float* po = out + (size_t)row * 128 + w * 32 + m;
                const float v0 = (cc[rt][0][r] + blv0) * inv;
                const float v1 = (cc[rt][1][r] + blv1) * inv;
                po[0]  = v0;
                po[16] = v1;
                s0 += v0; q0 += v0 * v0;
                s1 += v1; q1 += v1 * v1;
            }
        }
    }

    s0 += __shfl_down(s0, 32); q0 += __shfl_down(q0, 32);
    s0 += __shfl_down(s0, 16); q0 += __shfl_down(q0, 16);
    s1 += __shfl_down(s1, 32); q1 += __shfl_down(q1, 32);
    s1 += __shfl_down(s1, 16); q1 += __shfl_down(q1, 16);
    if (lane < 16) {
        atomicAdd(colsum + w * 32 + lane, s0);
        atomicAdd(colsq  + w * 32 + lane, q0);
        atomicAdd(colsum + w * 32 + 16 + lane, s1);
        atomicAdd(colsq  + w * 32 + 16 + lane, q1);
    }
}

// ---------------------------------------------------------------------------
// K7: BatchNorm (batch stats) + ReLU, in place on d_out.
// ---------------------------------------------------------------------------
__global__ __launch_bounds__(256) void k_bn_relu(
    float* __restrict__ out, const float* __restrict__ colsum,
    const float* __restrict__ colsq, const float* __restrict__ gamma,
    const float* __restrict__ beta)
{
    __shared__ float sc[128], sh[128];
    const int tid = threadIdx.x;
    if (tid < 128) {
        const float mean = colsum[tid] * (1.0f / NN);
        const float var = colsq[tid] * (1.0f / NN) - mean * mean;
        const float g = gamma[tid] * rsqrtf(var + 1e-5f);
        sc[tid] = g;
        sh[tid] = beta[tid] - mean * g;
    }
    __syncthreads();
    const int total = NN * 32;
    for (int i = blockIdx.x * 256 + tid; i < total; i += gridDim.x * 256) {
        const int c = (i & 31) << 2;
        float4 v = *(float4*)(out + (size_t)i * 4);
        v.x = fmaxf(fmaf(v.x, sc[c + 0], sh[c + 0]), 0.f);
        v.y = fmaxf(fmaf(v.y, sc[c + 1], sh[c + 1]), 0.f);
        v.z = fmaxf(fmaf(v.z, sc[c + 2], sh[c + 2]), 0.f);
        v.w = fmaxf(fmaf(v.w, sc[c + 3], sh[c + 3]), 0.f);
        *(float4*)(out + (size_t)i * 4) = v;
    }
}

extern "C" void kernel_launch(void* const* d_in, const int* in_sizes, int n_in,
                              void* d_out, int out_size, void* d_ws, size_t ws_size,
                              hipStream_t stream)
{
    const float* X      = (const float*)d_in[0];
    const float* bases  = (const float*)d_in[1];
    const float* coeff  = (const float*)d_in[2];
    const float* Wl     = (const float*)d_in[3];
    const float* bl     = (const float*)d_in[4];
    const float* gamma  = (const float*)d_in[5];
    const float* beta   = (const float*)d_in[6];
    const int*   eidx   = (const int*)d_in[7];
    const int*   etype  = (const int*)d_in[8];
    float* out = (float*)d_out;

    float* ws = (float*)d_ws;
    ushort_t* WT     = (ushort_t*)(ws + WT_OFF);
    ushort_t* XG     = (ushort_t*)(ws + XG_OFF);
    ushort_t* Xbf    = (ushort_t*)(ws + XBF_OFF);
    int*      cnt    = (int*)(ws + CNT_OFF);
    int*      curs   = (int*)(ws + CUR_OFF);
    int*      bsum   = (int*)(ws + BSUM_OFF);
    int*      bscan  = (int*)(ws + BSCN_OFF);
    float*    colsum = ws + CS_OFF;
    float*    colsq  = ws + CSQ_OFF;
    uint32_t* epack  = (uint32_t*)d_out;   // dead before k_gemm_f writes out

    // zero cnt..colsq
    hipMemsetAsync(cnt, 0, (CSQ_OFF + 128 - CNT_OFF) * sizeof(float), stream);

    const int nblk_scan = (NN + 511) / 512;   // 98

    k_prep<<<(128 * 640 + 255) / 256, 256, 0, stream>>>(Wl, bases, WT);
    k_cast<<<3125, 256, 0, stream>>>(X, Xbf, XG);
    k_hist<<<512, 256, 0, stream>>>(eidx, cnt);
    k_scan1<<<nblk_scan, 256, 0, stream>>>(cnt, curs, bsum);
    k_scan2<<<1, 128, 0, stream>>>(bsum, bscan, nblk_scan);
    k_scan3<<<nblk_scan, 256, 0, stream>>>(curs, bscan);
    k_scatter<<<512, 256, 0, stream>>>(eidx, etype, curs, epack);
    k_gather<<<3125, 256, 0, stream>>>(Xbf, epack, cnt, curs, coeff, XG);
    k_gemm_f<<<1563, 256, 0, stream>>>(XG, WT, bl, cnt, out, colsum, colsq);
    k_bn_relu<<<1024, 256, 0, stream>>>(out, colsum, colsq, gamma, beta);
}

// Round 11
// 281.068 us; speedup vs baseline: 1.0888x; 1.0888x over previous
//
#include <hip/hip_runtime.h>
#include <cstdint>

#define NN 50000
#define NE 600000

typedef unsigned short ushort_t;
typedef __bf16 bf16_t;
typedef __attribute__((ext_vector_type(8))) bf16_t bf16x8;
typedef __attribute__((ext_vector_type(8))) ushort_t ushort8;
typedef __attribute__((ext_vector_type(4))) float f32x4;

// ---- ws layout (float offsets), extent 19,341,472 fl = 77.37 MB ----
// WT   : [128 cols][640 k] bf16     @ 0           (81,920 ushorts = 40,960 fl)
// XG   : [3125 tiles][80 g][16 rows][8] bf16 @ 40,960   (32M ushorts = 16M fl)
//        g 0..15 = X k-cols 0..127; g 16..79 = G (4 bases x 128), kk = g*8
// Xbf  : [NN][128] bf16 (node-major, gather source) @ 16,040,960  (3.2M fl)
// cnt  : [NN] i32                   @ 19,240,960
// curs : [NN] i32                   @ 19,290,960
// bsum/bscan : 128+128 i32          @ 19,340,960 / 19,341,088
// colsum/colsq : 128+128 f32        @ 19,341,216 / 19,341,344
#define WT_OFF   0ul
#define XG_OFF   40960ul
#define XBF_OFF  16040960ul
#define CNT_OFF  19240960ul
#define CUR_OFF  19290960ul
#define BSUM_OFF 19340960ul
#define BSCN_OFF 19341088ul
#define CS_OFF   19341216ul
#define CSQ_OFF  19341344ul
// d_out transient: epack [NE] u32 @ 0 (scatter -> gather; dead before k_gemm_f)

__device__ __forceinline__ float2 bf2_to_f2(uint32_t u) {
    float2 r;
    r.x = __uint_as_float(u << 16);
    r.y = __uint_as_float(u & 0xffff0000u);
    return r;
}

__device__ __forceinline__ ushort_t f2bf(float f) {
    uint32_t u = __float_as_uint(f);
    u = (u + 0x7fffu + ((u >> 16) & 1u)) >> 16;   // RNE
    return (ushort_t)u;
}

__device__ __forceinline__ uint32_t f2bf2(float x, float y) {
    return (uint32_t)f2bf(x) | ((uint32_t)f2bf(y) << 16);
}

__device__ __forceinline__ void async_copy16(const void* g, void* l) {
    __builtin_amdgcn_global_load_lds(
        (const __attribute__((address_space(1))) void*)g,
        (__attribute__((address_space(3))) void*)l, 16, 0, 0);
}

// ---------------------------------------------------------------------------
// K0: WT[n][kk] bf16; kk<128 -> Wl[kk][n]; kk>=128: j=kk-128 (=b*128+i) ->
// bases[b][i][n].  kk-order matches XG fragment order (kk = g*8).
// ---------------------------------------------------------------------------
__global__ __launch_bounds__(256) void k_prep(
    const float* __restrict__ Wl, const float* __restrict__ bases,
    ushort_t* __restrict__ WT)
{
    const int i = blockIdx.x * 256 + threadIdx.x;
    if (i >= 128 * 640) return;
    const int n = i / 640;
    const int kk = i - n * 640;
    float v;
    if (kk < 128) v = Wl[kk * 128 + n];
    else {
        const int j = kk - 128;
        v = bases[(size_t)(j >> 7) * 16384 + (j & 127) * 128 + n];
    }
    WT[i] = f2bf(v);
}

// ---------------------------------------------------------------------------
// K0b: per 16-node tile: write Xbf (node-major) + XG X-part (fragment order)
// via an LDS transpose.
// ---------------------------------------------------------------------------
__global__ __launch_bounds__(256) void k_cast(
    const float* __restrict__ X, ushort_t* __restrict__ Xbf,
    ushort_t* __restrict__ XG)
{
    __shared__ ushort_t L[16][136];
    const int tid = threadIdx.x;
    const int tile = blockIdx.x;
    {
        const int row = tid >> 4, gc = tid & 15;
        const int node = tile * 16 + row;           // grid=3125 -> node<NN
        const float4* p = (const float4*)(X + (size_t)node * 128 + gc * 8);
        const float4 a = p[0], b = p[1];
        ushort_t t8[8] = { f2bf(a.x), f2bf(a.y), f2bf(a.z), f2bf(a.w),
                           f2bf(b.x), f2bf(b.y), f2bf(b.z), f2bf(b.w) };
        const uint4 v = *(const uint4*)t8;
        *(uint4*)&L[row][gc * 8] = v;
        *(uint4*)(Xbf + (size_t)node * 128 + gc * 8) = v;   // coalesced
    }
    __syncthreads();
    {
        const int g = tid >> 4, r2 = tid & 15;
        const uint4 u = *(const uint4*)&L[r2][g * 8];
        // lane-linear: g*256B + r2*16B -> contiguous 1KB per wave
        *(uint4*)(XG + (size_t)tile * 10240 + g * 128 + r2 * 8) = u;
    }
}

// ---------------------------------------------------------------------------
// K2: histogram of dst -> cnt
// ---------------------------------------------------------------------------
__global__ __launch_bounds__(256) void k_hist(
    const int* __restrict__ eidx, int* __restrict__ cnt)
{
    const int* __restrict__ dst = eidx + NE;
    for (int e = blockIdx.x * 256 + threadIdx.x; e < NE; e += gridDim.x * 256)
        atomicAdd(cnt + dst[e], 1);
}

// ---------------------------------------------------------------------------
// K3a/b/c: exclusive scan of cnt -> curs
// ---------------------------------------------------------------------------
__global__ __launch_bounds__(256) void k_scan1(
    const int* __restrict__ cnt, int* __restrict__ curs, int* __restrict__ bsum)
{
    __shared__ int sh[256];
    const int tid = threadIdx.x;
    const int i0 = blockIdx.x * 512 + tid * 2;
    const int v0 = (i0 < NN) ? cnt[i0] : 0;
    const int v1 = (i0 + 1 < NN) ? cnt[i0 + 1] : 0;
    int s = v0 + v1;
    sh[tid] = s;
    __syncthreads();
#pragma unroll
    for (int off = 1; off < 256; off <<= 1) {
        int t = (tid >= off) ? sh[tid - off] : 0;
        __syncthreads();
        sh[tid] += t;
        __syncthreads();
    }
    const int excl = sh[tid] - s;
    if (i0 < NN) curs[i0] = excl;
    if (i0 + 1 < NN) curs[i0 + 1] = excl + v0;
    if (tid == 255) bsum[blockIdx.x] = sh[255];
}

__global__ __launch_bounds__(128) void k_scan2(
    const int* __restrict__ bsum, int* __restrict__ bscan, int nblk)
{
    __shared__ int sh[128];
    const int tid = threadIdx.x;
    int v = (tid < nblk) ? bsum[tid] : 0;
    sh[tid] = v;
    __syncthreads();
#pragma unroll
    for (int off = 1; off < 128; off <<= 1) {
        int t = (tid >= off) ? sh[tid - off] : 0;
        __syncthreads();
        sh[tid] += t;
        __syncthreads();
    }
    if (tid < nblk) bscan[tid] = sh[tid] - v;
}

__global__ __launch_bounds__(256) void k_scan3(
    int* __restrict__ curs, const int* __restrict__ bscan)
{
    const int add = bscan[blockIdx.x];
    const int i0 = blockIdx.x * 512 + threadIdx.x * 2;
    if (i0 < NN) curs[i0] += add;
    if (i0 + 1 < NN) curs[i0 + 1] += add;
}

// ---------------------------------------------------------------------------
// K4: scatter edges into CSR slots. epack = src | (type<<16).
// ---------------------------------------------------------------------------
__global__ __launch_bounds__(256) void k_scatter(
    const int* __restrict__ eidx, const int* __restrict__ etype,
    int* __restrict__ curs, uint32_t* __restrict__ epack)
{
    const int* __restrict__ src = eidx;
    const int* __restrict__ dst = eidx + NE;
    for (int e = blockIdx.x * 256 + threadIdx.x; e < NE; e += gridDim.x * 256) {
        const int d = dst[e];
        const int pos = atomicAdd(curs + d, 1);
        epack[pos] = (uint32_t)src[e] | ((uint32_t)etype[e] << 16);
    }
}

// ---------------------------------------------------------------------------
// K5: gather, subgroup-parallel. 16 lanes per node, 4 nodes per wave.
// Lane k owns cols 8k..8k+7 (one 16B Xbf load/edge, 256B contiguous per
// subgroup) and all 4 bases (32 f32 acc). Final stores: one uint4 per basis
// per lane; 4 subgroups cover rows w*4..w*4+3 -> every 64B line written
// whole in a single instruction (kills the R10 5x write amplification).
// ---------------------------------------------------------------------------
__device__ __forceinline__ void edge_accum8(
    uint32_t ep, const ushort_t* __restrict__ Xbf,
    const float* __restrict__ coeff, int k, float* m)   // m[32]
{
    const int s = ep & 0xffff;
    const int t = ep >> 16;
    const float4 cw = *(const float4*)(coeff + t * 4);
    const uint4 xv = *(const uint4*)(Xbf + (size_t)s * 128 + k * 8);
    float x[8];
    float2 p;
    p = bf2_to_f2(xv.x); x[0] = p.x; x[1] = p.y;
    p = bf2_to_f2(xv.y); x[2] = p.x; x[3] = p.y;
    p = bf2_to_f2(xv.z); x[4] = p.x; x[5] = p.y;
    p = bf2_to_f2(xv.w); x[6] = p.x; x[7] = p.y;
#pragma unroll
    for (int c = 0; c < 8; ++c) {
        m[0 * 8 + c] += cw.x * x[c];
        m[1 * 8 + c] += cw.y * x[c];
        m[2 * 8 + c] += cw.z * x[c];
        m[3 * 8 + c] += cw.w * x[c];
    }
}

__global__ __launch_bounds__(256) void k_gather(
    const ushort_t* __restrict__ Xbf, const uint32_t* __restrict__ epack,
    const int* __restrict__ cnt, const int* __restrict__ curs,
    const float* __restrict__ coeff, ushort_t* __restrict__ XG)
{
    const int lane = threadIdx.x & 63;
    const int w = threadIdx.x >> 6;
    const int sub = lane >> 4;     // node within wave's 4
    const int k = lane & 15;       // col block (8 cols)
    const int tile = blockIdx.x;
    const int d = tile * 16 + w * 4 + sub;   // grid=3125 -> d<NN

    const int n = cnt[d];
    const int end = curs[d];       // post-scatter: end offset
    int j = end - n;

    float m[32];
#pragma unroll
    for (int i = 0; i < 32; ++i) m[i] = 0.f;

    for (; j + 3 < end; j += 4) {
        const uint32_t e0 = epack[j];
        const uint32_t e1 = epack[j + 1];
        const uint32_t e2 = epack[j + 2];
        const uint32_t e3 = epack[j + 3];
        edge_accum8(e0, Xbf, coeff, k, m);
        edge_accum8(e1, Xbf, coeff, k, m);
        edge_accum8(e2, Xbf, coeff, k, m);
        edge_accum8(e3, Xbf, coeff, k, m);
    }
    for (; j < end; ++j) edge_accum8(epack[j], Xbf, coeff, k, m);

    uint32_t* gb = (uint32_t*)(XG + (size_t)tile * 10240);
#pragma unroll
    for (int b = 0; b < 4; ++b) {
        uint4 v;
        v.x = f2bf2(m[b * 8 + 0], m[b * 8 + 1]);
        v.y = f2bf2(m[b * 8 + 2], m[b * 8 + 3]);
        v.z = f2bf2(m[b * 8 + 4], m[b * 8 + 5]);
        v.w = f2bf2(m[b * 8 + 6], m[b * 8 + 7]);
        *(uint4*)(gb + (16 + b * 16 + k) * 64 + (w * 4 + sub) * 4) = v;
    }
}

// ---------------------------------------------------------------------------
// K6: FUSED projection. Block = 32 rows (2 tiles) x 128 cols, grid 1563.
// Stage: 40 x 1KB async global_load_lds; LDS layout == lane order ->
// ds_read_b128 conflict-free. 4 waves, wave = 32 cols; K=640 unrolled.
// Epilogue: degree-norm + column stats.
// ---------------------------------------------------------------------------
__global__ __launch_bounds__(256) void k_gemm_f(
    const ushort_t* __restrict__ XG, const ushort_t* __restrict__ WT,
    const float* __restrict__ bl, const int* __restrict__ cnt,
    float* __restrict__ out, float* __restrict__ colsum,
    float* __restrict__ colsq)
{
    __shared__ ushort_t As[2][10240];
    const int tid = threadIdx.x;
    const int lane = tid & 63;
    const int w = tid >> 6;
    const int row0 = blockIdx.x * 32;
    const int tile0 = blockIdx.x * 2;

    // async stage (tile 3125 OOB reads land in Xbf region; rows guarded)
#pragma unroll
    for (int k = 0; k < 10; ++k) {
        const int s = w * 10 + k;
        const int tl = s >= 20 ? 1 : 0;
        const int off = s - tl * 20;
        const ushort_t* src = XG + (size_t)(tile0 + tl) * 10240 + off * 512 + lane * 8;
        async_copy16(src, &As[tl][off * 512]);
    }
    __syncthreads();   // drains vmcnt

    const int m = lane & 15;
    const int quad = lane >> 4;
    const ushort_t* bp0 = WT + (size_t)(w * 32 + m) * 640 + quad * 8;
    const ushort_t* bp1 = bp0 + 16 * 640;

    f32x4 cc[2][2];
#pragma unroll
    for (int rt = 0; rt < 2; ++rt)
#pragma unroll
        for (int ct = 0; ct < 2; ++ct)
#pragma unroll
            for (int i = 0; i < 4; ++i) cc[rt][ct][i] = 0.f;

#pragma unroll
    for (int c = 0; c < 20; ++c) {
        const bf16x8 b0 = __builtin_bit_cast(bf16x8, *(const ushort8*)(bp0 + c * 32));
        const bf16x8 b1 = __builtin_bit_cast(bf16x8, *(const ushort8*)(bp1 + c * 32));
        const int aoff = (c * 4 + quad) * 128 + m * 8;   // == c*1024B + lane*16B
        const bf16x8 a0 = __builtin_bit_cast(bf16x8, *(const ushort8*)&As[0][aoff]);
        const bf16x8 a1 = __builtin_bit_cast(bf16x8, *(const ushort8*)&As[1][aoff]);
        cc[0][0] = __builtin_amdgcn_mfma_f32_16x16x32_bf16(a0, b0, cc[0][0], 0, 0, 0);
        cc[0][1] = __builtin_amdgcn_mfma_f32_16x16x32_bf16(a0, b1, cc[0][1], 0, 0, 0);
        cc[1][0] = __builtin_amdgcn_mfma_f32_16x16x32_bf16(a1, b0, cc[1][0], 0, 0, 0);
        cc[1][1] = __builtin_amdgcn_mfma_f32_16x16x32_bf16(a1, b1, cc[1][1], 0, 0, 0);
    }

    // epilogue: degree-norm, store, column stats
    const float blv0 = bl[w * 32 + m];
    const float blv1 = bl[w * 32 + 16 + m];
    float s0 = 0.f, q0 = 0.f, s1 = 0.f, q1 = 0.f;

#pragma unroll
    for (int rt = 0; rt < 2; ++rt) {
        const int rowb = row0 + rt * 16 + quad * 4;
#pragma unroll
        for (int r = 0; r < 4; ++r) {
            const int row = rowb + r;
            if (row < NN) {
                const int dg = cnt[row];
                const float inv = 1.0f / (float)((dg > 0) ? dg : 1);
                float* po = out + (size_t)row * 128 + w * 32 + m;
                const float v0 = (cc[rt][0][r] + blv0) * inv;
                const float v1 = (cc[rt][1][r] + blv1) * inv;
                po[0]  = v0;
                po[16] = v1;
                s0 += v0; q0 += v0 * v0;
                s1 += v1; q1 += v1 * v1;
            }
        }
    }

    s0 += __shfl_down(s0, 32); q0 += __shfl_down(q0, 32);
    s0 += __shfl_down(s0, 16); q0 += __shfl_down(q0, 16);
    s1 += __shfl_down(s1, 32); q1 += __shfl_down(q1, 32);
    s1 += __shfl_down(s1, 16); q1 += __shfl_down(q1, 16);
    if (lane < 16) {
        atomicAdd(colsum + w * 32 + lane, s0);
        atomicAdd(colsq  + w * 32 + lane, q0);
        atomicAdd(colsum + w * 32 + 16 + lane, s1);
        atomicAdd(colsq  + w * 32 + 16 + lane, q1);
    }
}

// ---------------------------------------------------------------------------
// K7: BatchNorm (batch stats) + ReLU, in place on d_out.
// ---------------------------------------------------------------------------
__global__ __launch_bounds__(256) void k_bn_relu(
    float* __restrict__ out, const float* __restrict__ colsum,
    const float* __restrict__ colsq, const float* __restrict__ gamma,
    const float* __restrict__ beta)
{
    __shared__ float sc[128], sh[128];
    const int tid = threadIdx.x;
    if (tid < 128) {
        const float mean = colsum[tid] * (1.0f / NN);
        const float var = colsq[tid] * (1.0f / NN) - mean * mean;
        const float g = gamma[tid] * rsqrtf(var + 1e-5f);
        sc[tid] = g;
        sh[tid] = beta[tid] - mean * g;
    }
    __syncthreads();
    const int total = NN * 32;
    for (int i = blockIdx.x * 256 + tid; i < total; i += gridDim.x * 256) {
        const int c = (i & 31) << 2;
        float4 v = *(float4*)(out + (size_t)i * 4);
        v.x = fmaxf(fmaf(v.x, sc[c + 0], sh[c + 0]), 0.f);
        v.y = fmaxf(fmaf(v.y, sc[c + 1], sh[c + 1]), 0.f);
        v.z = fmaxf(fmaf(v.z, sc[c + 2], sh[c + 2]), 0.f);
        v.w = fmaxf(fmaf(v.w, sc[c + 3], sh[c + 3]), 0.f);
        *(float4*)(out + (size_t)i * 4) = v;
    }
}

extern "C" void kernel_launch(void* const* d_in, const int* in_sizes, int n_in,
                              void* d_out, int out_size, void* d_ws, size_t ws_size,
                              hipStream_t stream)
{
    const float* X      = (const float*)d_in[0];
    const float* bases  = (const float*)d_in[1];
    const float* coeff  = (const float*)d_in[2];
    const float* Wl     = (const float*)d_in[3];
    const float* bl     = (const float*)d_in[4];
    const float* gamma  = (const float*)d_in[5];
    const float* beta   = (const float*)d_in[6];
    const int*   eidx   = (const int*)d_in[7];
    const int*   etype  = (const int*)d_in[8];
    float* out = (float*)d_out;

    float* ws = (float*)d_ws;
    ushort_t* WT     = (ushort_t*)(ws + WT_OFF);
    ushort_t* XG     = (ushort_t*)(ws + XG_OFF);
    ushort_t* Xbf    = (ushort_t*)(ws + XBF_OFF);
    int*      cnt    = (int*)(ws + CNT_OFF);
    int*      curs   = (int*)(ws + CUR_OFF);
    int*      bsum   = (int*)(ws + BSUM_OFF);
    int*      bscan  = (int*)(ws + BSCN_OFF);
    float*    colsum = ws + CS_OFF;
    float*    colsq  = ws + CSQ_OFF;
    uint32_t* epack  = (uint32_t*)d_out;   // dead before k_gemm_f writes out

    // zero cnt..colsq
    hipMemsetAsync(cnt, 0, (CSQ_OFF + 128 - CNT_OFF) * sizeof(float), stream);

    const int nblk_scan = (NN + 511) / 512;   // 98

    k_prep<<<(128 * 640 + 255) / 256, 256, 0, stream>>>(Wl, bases, WT);
    k_cast<<<3125, 256, 0, stream>>>(X, Xbf, XG);
    k_hist<<<512, 256, 0, stream>>>(eidx, cnt);
    k_scan1<<<nblk_scan, 256, 0, stream>>>(cnt, curs, bsum);
    k_scan2<<<1, 128, 0, stream>>>(bsum, bscan, nblk_scan);
    k_scan3<<<nblk_scan, 256, 0, stream>>>(curs, bscan);
    k_scatter<<<512, 256, 0, stream>>>(eidx, etype, curs, epack);
    k_gather<<<3125, 256, 0, stream>>>(Xbf, epack, cnt, curs, coeff, XG);
    k_gemm_f<<<1563, 256, 0, stream>>>(XG, WT, bl, cnt, out, colsum, colsq);
    k_bn_relu<<<1024, 256, 0, stream>>>(out, colsum, colsq, gamma, beta);
}